// Round 1
// baseline (3058.766 us; speedup 1.0000x reference)
//
#include <hip/hip_runtime.h>

#define KT 8
#define NN 255
#define NL 256
#define LL 16
#define DD 512
#define BB 32
#define TT 2048
#define MM (BB*TT)

static __device__ __forceinline__ float sigmoidf_(float x) {
    return 1.0f / (1.0f + __expf(-x));
}

// softmax over last dim of pi: sp[k][leaf][l]
__global__ void k_prep_sp(const float* __restrict__ pi, float* __restrict__ sp) {
    int g = blockIdx.x * blockDim.x + threadIdx.x;   // one thread per (k,leaf)
    if (g >= KT * NL) return;
    const float* p = pi + (size_t)g * LL;
    float v[LL];
    float mx = -1e30f;
    #pragma unroll
    for (int l = 0; l < LL; ++l) { v[l] = p[l]; mx = fmaxf(mx, v[l]); }
    float s = 0.f;
    #pragma unroll
    for (int l = 0; l < LL; ++l) { v[l] = __expf(v[l] - mx); s += v[l]; }
    const float inv = 1.0f / s;
    float* o = sp + (size_t)g * LL;
    #pragma unroll
    for (int l = 0; l < LL; ++l) o[l] = v[l] * inv;
}

// Wt[k][f][n] (n padded to 256, pad = 0) from W[k][n][f]
__global__ void k_prep_wt(const float* __restrict__ W, float* __restrict__ Wt) {
    int g = blockIdx.x * blockDim.x + threadIdx.x;
    int n = g & (NL - 1);
    int f = (g >> 8) & (DD - 1);
    int k = g >> 17;               // 256*512 = 2^17
    if (k >= KT) return;
    float v = 0.f;
    if (n < NN) v = W[((size_t)k * NN + n) * DD + f];
    Wt[g] = v;
}

// Fused GEMM(64x255x512) + sigmoid + tree + pi-projection per (m-tile, k)
__launch_bounds__(256, 2)
__global__ void k_forest(const float* __restrict__ x, const float* __restrict__ Wt,
                         const float* __restrict__ bias, const float* __restrict__ sp,
                         float* __restrict__ tp) {
    __shared__ float lds[16384];   // 64 KB union
    float* xs = lds;               // [64][36] during GEMM
    float* wt = lds + 2304;        // [32][256] during GEMM
    float* dl = lds;               // [64][256] after GEMM (XOR-swizzled cols)

    const int tid = threadIdx.x;
    const int kt  = blockIdx.y;
    const int m0  = blockIdx.x * 64;
    const int tn  = tid & 31;      // n-group: n = tn*8 + j
    const int tm  = tid >> 5;      // m-group: m = tm*8 + i

    float acc[8][8];
    #pragma unroll
    for (int i = 0; i < 8; ++i)
        #pragma unroll
        for (int j = 0; j < 8; ++j) acc[i][j] = 0.f;

    const int sr = tid >> 3;       // x-stage row 0..31
    const int sc = tid & 7;        // x-stage float4 col 0..7

    for (int kb = 0; kb < 16; ++kb) {
        const int f0 = kb * 32;
        __syncthreads();
        // stage x tile 64x32 -> xs[64][36] (row-major, padded)
        #pragma unroll
        for (int p = 0; p < 2; ++p) {
            const int row = sr + p * 32;
            const float4 v = *reinterpret_cast<const float4*>(
                &x[(size_t)(m0 + row) * DD + f0 + sc * 4]);
            *reinterpret_cast<float4*>(&xs[row * 36 + sc * 4]) = v;
        }
        // stage Wt tile 32x256 (contiguous 8192 floats)
        {
            const float* wsrc = &Wt[((size_t)kt * DD + f0) * NL];
            #pragma unroll
            for (int i = 0; i < 8; ++i) {
                const int idx = (i * 256 + tid) * 4;
                *reinterpret_cast<float4*>(&wt[idx]) =
                    *reinterpret_cast<const float4*>(&wsrc[idx]);
            }
        }
        __syncthreads();
        #pragma unroll
        for (int kk = 0; kk < 32; ++kk) {
            float a[8];
            #pragma unroll
            for (int i = 0; i < 8; ++i) a[i] = xs[(tm * 8 + i) * 36 + kk];
            const float4 b0 = *reinterpret_cast<const float4*>(&wt[kk * 256 + tn * 8]);
            const float4 b1 = *reinterpret_cast<const float4*>(&wt[kk * 256 + tn * 8 + 4]);
            const float bb[8] = {b0.x, b0.y, b0.z, b0.w, b1.x, b1.y, b1.z, b1.w};
            #pragma unroll
            for (int i = 0; i < 8; ++i)
                #pragma unroll
                for (int j = 0; j < 8; ++j)
                    acc[i][j] = fmaf(a[i], bb[j], acc[i][j]);
        }
    }
    __syncthreads();
    // bias + sigmoid -> dl (cols XORed with (m&7)<<2 to avoid bank conflicts)
    #pragma unroll
    for (int i = 0; i < 8; ++i) {
        const int m  = tm * 8 + i;
        const int sw = (i & 7) << 2;         // == (m&7)<<2
        #pragma unroll
        for (int jj = 0; jj < 2; ++jj) {
            float t[4];
            #pragma unroll
            for (int u = 0; u < 4; ++u) {
                const int n = tn * 8 + jj * 4 + u;
                float lg = acc[i][jj * 4 + u];
                lg += (n < NN) ? bias[kt * NN + n] : 0.f;
                t[u] = sigmoidf_(lg);
            }
            float4 v; v.x = t[0]; v.y = t[1]; v.z = t[2]; v.w = t[3];
            const int col = (tn * 8 + jj * 4) ^ sw;   // XOR hits bits 2..4 only
            *reinterpret_cast<float4*>(&dl[m * 256 + col]) = v;
        }
    }
    __syncthreads();
    // tree walk + projection onto L: 4 threads per m, 64 leaves each
    const int mt = tid >> 2;       // 0..63
    const int q  = tid & 3;        // leaf quarter
    const float* dm  = &dl[mt * 256];
    const int swm = (mt & 7) << 2;
    const float* spk = &sp[(size_t)kt * NL * LL];
    float tpl[16];
    #pragma unroll
    for (int l = 0; l < 16; ++l) tpl[l] = 0.f;
    for (int j = 0; j < 64; ++j) {
        const int leaf = q * 64 + j;
        float mu = 1.f;
        #pragma unroll
        for (int lvl = 0; lvl < 8; ++lvl) {
            const int node = (1 << lvl) - 1 + (leaf >> (8 - lvl));
            const float dv = dm[node ^ swm];
            mu *= ((leaf >> (7 - lvl)) & 1) ? (1.f - dv) : dv;
        }
        const float4 s0 = *reinterpret_cast<const float4*>(&spk[leaf * 16]);
        const float4 s1 = *reinterpret_cast<const float4*>(&spk[leaf * 16 + 4]);
        const float4 s2 = *reinterpret_cast<const float4*>(&spk[leaf * 16 + 8]);
        const float4 s3 = *reinterpret_cast<const float4*>(&spk[leaf * 16 + 12]);
        tpl[0]  += mu * s0.x; tpl[1]  += mu * s0.y; tpl[2]  += mu * s0.z; tpl[3]  += mu * s0.w;
        tpl[4]  += mu * s1.x; tpl[5]  += mu * s1.y; tpl[6]  += mu * s1.z; tpl[7]  += mu * s1.w;
        tpl[8]  += mu * s2.x; tpl[9]  += mu * s2.y; tpl[10] += mu * s2.z; tpl[11] += mu * s2.w;
        tpl[12] += mu * s3.x; tpl[13] += mu * s3.y; tpl[14] += mu * s3.z; tpl[15] += mu * s3.w;
    }
    #pragma unroll
    for (int l = 0; l < 16; ++l) {
        tpl[l] += __shfl_xor(tpl[l], 1, 4);
        tpl[l] += __shfl_xor(tpl[l], 2, 4);
    }
    // tp layout: [m][l][k]  (k innermost, 128 floats per m)
    float* dst = &tp[(size_t)(m0 + mt) * 128];
    #pragma unroll
    for (int u = 0; u < 4; ++u) {
        const int l = q * 4 + u;
        dst[l * 8 + kt] = tpl[l];
    }
}

// sequential scan over T per batch row; lane l owns output channel l
__global__ void k_scan(const float* __restrict__ tp, float* __restrict__ out) {
    const int b = blockIdx.x;
    const int l = threadIdx.x;
    if (l >= 16) return;
    const float* base = &tp[(size_t)b * TT * 128];
    float tk[8];
    #pragma unroll
    for (int k = 0; k < 8; ++k) tk[k] = 1.0f / 16.0f;
    float4 c0 = *reinterpret_cast<const float4*>(&base[l * 8]);
    float4 c1 = *reinterpret_cast<const float4*>(&base[l * 8 + 4]);
    for (int t = 0; t < TT; ++t) {
        float4 n0, n1;
        if (t + 1 < TT) {
            n0 = *reinterpret_cast<const float4*>(&base[(size_t)(t + 1) * 128 + l * 8]);
            n1 = *reinterpret_cast<const float4*>(&base[(size_t)(t + 1) * 128 + l * 8 + 4]);
        }
        const float nw = c0.x * tk[0] + c0.y * tk[1] + c0.z * tk[2] + c0.w * tk[3]
                       + c1.x * tk[4] + c1.y * tk[5] + c1.z * tk[6] + c1.w * tk[7];
        out[((size_t)b * TT + t) * 16 + l] = nw;
        // tmp = softmax(exp(new)); max-subtraction unnecessary (new <= 1 -> w <= e^e)
        const float w = __expf(__expf(nw));
        float s = w;
        s += __shfl_xor(s, 1, 16);
        s += __shfl_xor(s, 2, 16);
        s += __shfl_xor(s, 4, 16);
        s += __shfl_xor(s, 8, 16);
        const float tl = w / s;
        #pragma unroll
        for (int k = 0; k < 8; ++k) tk[k] = __shfl(tl, k, 16);
        c0 = n0; c1 = n1;
    }
}

extern "C" void kernel_launch(void* const* d_in, const int* in_sizes, int n_in,
                              void* d_out, int out_size, void* d_ws, size_t ws_size,
                              hipStream_t stream) {
    const float* x  = (const float*)d_in[0];
    const float* W  = (const float*)d_in[1];
    const float* b  = (const float*)d_in[2];
    const float* pi = (const float*)d_in[3];
    float* ws = (float*)d_ws;
    float* sp = ws;                            // 32768 floats
    float* Wt = ws + 32768;                    // 1048576 floats
    float* tp = ws + 32768 + 1048576;          // 8388608 floats
    float* out = (float*)d_out;

    k_prep_sp<<<dim3((KT * NL + 255) / 256), dim3(256), 0, stream>>>(pi, sp);
    k_prep_wt<<<dim3((KT * DD * NL) / 256), dim3(256), 0, stream>>>(W, Wt);
    k_forest<<<dim3(MM / 64, KT), dim3(256), 0, stream>>>(x, Wt, b, sp, tp);
    k_scan<<<dim3(BB), dim3(64), 0, stream>>>(tp, out);
}

// Round 2
// 1836.366 us; speedup vs baseline: 1.6657x; 1.6657x over previous
//
#include <hip/hip_runtime.h>

#define KT 8
#define NN 255
#define LL 16
#define DD 512
#define BB 32
#define TT 2048
#define MM (BB*TT)      // 65536

typedef short short8 __attribute__((ext_vector_type(8)));
typedef float floatx4 __attribute__((ext_vector_type(4)));

__device__ __forceinline__ unsigned bf16_rne(float v) {
    unsigned u = __float_as_uint(v);
    return (u + 0x7FFFu + ((u >> 16) & 1u)) >> 16;
}

// ---------------- prep: softmax(pi) with chunk swizzle: sp[kt][leaf][c^( (leaf>>4)&3 )]
__global__ void k_prep_sp(const float* __restrict__ pi, float* __restrict__ sp) {
    int g = blockIdx.x * blockDim.x + threadIdx.x;   // 2048 = KT*256
    int leaf = g & 255;
    const float* p = pi + (size_t)g * LL;
    float v[LL];
    float mx = -1e30f;
    #pragma unroll
    for (int l = 0; l < LL; ++l) { v[l] = p[l]; mx = fmaxf(mx, v[l]); }
    float s = 0.f;
    #pragma unroll
    for (int l = 0; l < LL; ++l) { v[l] = __expf(v[l] - mx); s += v[l]; }
    const float inv = 1.0f / s;
    float* o = sp + (size_t)(g >> 8) * 4096 + (size_t)leaf * 16;
    const int sw = (leaf >> 4) & 3;
    #pragma unroll
    for (int c = 0; c < 4; ++c)
        #pragma unroll
        for (int u = 0; u < 4; ++u)
            o[((c ^ sw) << 2) + u] = v[c * 4 + u] * inv;
}

// ---------------- prep: W -> MFMA B-fragment order, split bf16 hi/lo
// Bp layout: [kt][kb(16)][nt(16)][hl(2)][lane(64)][8 bf16]
__global__ void k_prep_b(const float* __restrict__ W, short* __restrict__ Bp) {
    int g = blockIdx.x * 256 + threadIdx.x;          // 131072
    int lane = g & 63;
    int nt = (g >> 6) & 15;
    int kb = (g >> 10) & 15;
    int kt = g >> 14;
    int n = nt * 16 + (lane & 15);
    int k0 = kb * 32 + ((lane >> 4) << 3);
    short8 hh = {0,0,0,0,0,0,0,0}, ll = {0,0,0,0,0,0,0,0};
    if (n < NN) {
        const float* wp = W + ((size_t)kt * NN + n) * DD + k0;
        floatx4 a = *(const floatx4*)wp;
        floatx4 b = *(const floatx4*)(wp + 4);
        float xv[8] = {a[0], a[1], a[2], a[3], b[0], b[1], b[2], b[3]};
        #pragma unroll
        for (int j = 0; j < 8; ++j) {
            unsigned h = bf16_rne(xv[j]);
            hh[j] = (short)h;
            float rest = xv[j] - __uint_as_float(h << 16);
            ll[j] = (short)bf16_rne(rest);
        }
    }
    size_t base = ((((size_t)kt * 16 + kb) * 16 + nt) * 2) * 64;   // in short8 units
    ((short8*)Bp)[base + lane] = hh;
    ((short8*)Bp)[base + 64 + lane] = ll;
}

// ---------------- fused forest kernel ----------------
__device__ __forceinline__ void load_a_raw(const float* xb, int kb, int lane, floatx4 xr[2][2]) {
    #pragma unroll
    for (int mt = 0; mt < 2; ++mt) {
        const float* row = xb + (size_t)(mt * 16 + (lane & 15)) * DD + kb * 32 + ((lane >> 4) << 3);
        xr[mt][0] = *(const floatx4*)row;
        xr[mt][1] = *(const floatx4*)(row + 4);
    }
}

__device__ __forceinline__ void gemm_step(const char* bufp, const floatx4 xr[2][2],
                                          floatx4 acc[2][8], int wc8, int lane) {
    short8 ah[2], al[2];
    #pragma unroll
    for (int mt = 0; mt < 2; ++mt) {
        #pragma unroll
        for (int j = 0; j < 8; ++j) {
            float v = xr[mt][j >> 2][j & 3];
            unsigned h = bf16_rne(v);
            ah[mt][j] = (short)h;
            al[mt][j] = (short)bf16_rne(v - __uint_as_float(h << 16));
        }
    }
    const short8* bp = (const short8*)bufp;
    #pragma unroll
    for (int nt = 0; nt < 8; ++nt) {
        short8 bh = bp[(size_t)((wc8 + nt) * 2 + 0) * 64 + lane];
        short8 bl = bp[(size_t)((wc8 + nt) * 2 + 1) * 64 + lane];
        #pragma unroll
        for (int mt = 0; mt < 2; ++mt) {
            acc[mt][nt] = __builtin_amdgcn_mfma_f32_16x16x32_bf16(ah[mt], bh, acc[mt][nt], 0, 0, 0);
            acc[mt][nt] = __builtin_amdgcn_mfma_f32_16x16x32_bf16(ah[mt], bl, acc[mt][nt], 0, 0, 0);
            acc[mt][nt] = __builtin_amdgcn_mfma_f32_16x16x32_bf16(al[mt], bh, acc[mt][nt], 0, 0, 0);
        }
    }
}

__launch_bounds__(512, 2)
__global__ void k_forest(const float* __restrict__ x, const short* __restrict__ Bp,
                         const float* __restrict__ bias, const float* __restrict__ spg,
                         float* __restrict__ tp) {
    __shared__ __align__(16) char smem[65536];
    const int tid  = threadIdx.x;
    const int lane = tid & 63;
    const int wv   = tid >> 6;
    const int wr   = wv >> 1;       // 0..3  (m-row of 32)
    const int wc   = wv & 1;        // 0..1  (n-col of 128)
    const int wc8  = wc * 8;
    const int kt   = blockIdx.x;    // tree (fastest -> XCD spread, B hot in L2)
    const int mb   = blockIdx.y;    // m-tile of 128

    const float* xb = x + ((size_t)mb * 128 + wr * 32) * DD;
    const floatx4* bsrc = (const floatx4*)Bp + (size_t)kt * 16 * 2048;  // per kb: 2048 float4 = 32KB

    // bias per lane for its 8 n-tiles
    float breg[8];
    #pragma unroll
    for (int nt = 0; nt < 8; ++nt) {
        int n = wc * 128 + nt * 16 + (lane & 15);
        breg[nt] = (n < NN) ? bias[kt * NN + n] : 0.f;
    }

    floatx4 acc[2][8];
    #pragma unroll
    for (int mt = 0; mt < 2; ++mt)
        #pragma unroll
        for (int nt = 0; nt < 8; ++nt)
            acc[mt][nt] = (floatx4){0.f, 0.f, 0.f, 0.f};

    floatx4 sreg[4];
    floatx4 xr[2][2], xn[2][2];

    // prologue: stage kb=0
    #pragma unroll
    for (int i = 0; i < 4; ++i) sreg[i] = bsrc[(size_t)0 * 2048 + i * 512 + tid];
    load_a_raw(xb, 0, lane, xr);
    {
        floatx4* dstb = (floatx4*)smem;
        #pragma unroll
        for (int i = 0; i < 4; ++i) dstb[i * 512 + tid] = sreg[i];
    }
    __syncthreads();

    #pragma unroll 1
    for (int kb2 = 0; kb2 < 8; ++kb2) {
        const int kbA = kb2 * 2;
        // phase A: compute kbA from buf0 (xr); prefetch kbA+1
        #pragma unroll
        for (int i = 0; i < 4; ++i) sreg[i] = bsrc[(size_t)(kbA + 1) * 2048 + i * 512 + tid];
        load_a_raw(xb, kbA + 1, lane, xn);
        gemm_step(smem, xr, acc, wc8, lane);
        {
            floatx4* dstb = (floatx4*)(smem + 32768);
            #pragma unroll
            for (int i = 0; i < 4; ++i) dstb[i * 512 + tid] = sreg[i];
        }
        __syncthreads();
        // phase B: compute kbA+1 from buf1 (xn); prefetch kbA+2
        if (kb2 < 7) {
            #pragma unroll
            for (int i = 0; i < 4; ++i) sreg[i] = bsrc[(size_t)(kbA + 2) * 2048 + i * 512 + tid];
            load_a_raw(xb, kbA + 2, lane, xr);
        }
        gemm_step(smem + 32768, xn, acc, wc8, lane);
        if (kb2 < 7) {
            floatx4* dstb = (floatx4*)smem;
            #pragma unroll
            for (int i = 0; i < 4; ++i) dstb[i * 512 + tid] = sreg[i];
        }
        __syncthreads();
    }

    // ---------------- epilogue ----------------
    float* dls = (float*)smem;                   // [32][260] fp32, +1 col offset
    float* spl = (float*)(smem + 33280);         // [256][16] fp32 (chunk-swizzled)

    // stage sp (16KB) via regs
    {
        const floatx4* ss = (const floatx4*)(spg + (size_t)kt * 4096);
        floatx4 t0 = ss[tid], t1 = ss[512 + tid];
        ((floatx4*)spl)[tid] = t0;
        ((floatx4*)spl)[512 + tid] = t1;
    }

    const int mloc = tid >> 4;    // 0..31
    const int qq   = tid & 15;

    #pragma unroll 1
    for (int p = 0; p < 4; ++p) {
        if (wr == p) {
            #pragma unroll
            for (int mt = 0; mt < 2; ++mt)
                #pragma unroll
                for (int nt = 0; nt < 8; ++nt)
                    #pragma unroll
                    for (int i = 0; i < 4; ++i) {
                        float lg = acc[mt][nt][i] + breg[nt];
                        float dv = 1.f / (1.f + __expf(-lg));
                        int mrow = mt * 16 + ((lane >> 4) << 2) + i;   // 0..31
                        int n = wc * 128 + nt * 16 + (lane & 15);
                        dls[mrow * 260 + 1 + n] = dv;
                    }
        }
        __syncthreads();

        const float* dm = dls + mloc * 260;
        // register-cached path nodes
        float n0 = dm[1];
        float n1 = dm[2 + (qq >> 3)];
        float n2 = dm[4 + (qq >> 2)];
        float n3 = dm[8 + (qq >> 1)];
        float v4 = dm[16 + qq];
        float v5a = dm[32 + 2 * qq], v5b = dm[33 + 2 * qq];
        floatx4 v6  = *(const floatx4*)(dm + 64 + 4 * qq);
        floatx4 v7a = *(const floatx4*)(dm + 128 + 8 * qq);
        floatx4 v7b = *(const floatx4*)(dm + 132 + 8 * qq);

        float P = ((qq >> 3) ? (1.f - n0) : n0)
                * (((qq >> 2) & 1) ? (1.f - n1) : n1)
                * (((qq >> 1) & 1) ? (1.f - n2) : n2)
                * ((qq & 1) ? (1.f - n3) : n3);

        float tpl[16];
        #pragma unroll
        for (int i = 0; i < 16; ++i) tpl[i] = 0.f;

        float p4 = 0.f, p5 = 0.f, p6;
        #pragma unroll
        for (int jj = 0; jj < 8; ++jj) {
            if ((jj & 3) == 0) p4 = P * ((jj >> 2) ? (1.f - v4) : v4);
            if ((jj & 1) == 0) {
                float vv5 = (jj >> 2) ? v5b : v5a;
                p5 = p4 * (((jj >> 1) & 1) ? (1.f - vv5) : vv5);
            }
            float vv6 = v6[jj >> 1];
            p6 = p5 * ((jj & 1) ? (1.f - vv6) : vv6);
            float vv7 = (jj < 4) ? v7a[jj & 3] : v7b[jj & 3];
            float mu0 = p6 * vv7;
            float mu1 = p6 * (1.f - vv7);
            const float* s0 = spl + (size_t)(qq * 16 + 2 * jj) * 16;
            const int sw = qq & 3;
            #pragma unroll
            for (int c = 0; c < 4; ++c) {
                int cc = (c ^ sw) << 2;
                floatx4 a = *(const floatx4*)(s0 + cc);
                floatx4 b = *(const floatx4*)(s0 + 16 + cc);
                #pragma unroll
                for (int u = 0; u < 4; ++u)
                    tpl[c * 4 + u] += mu0 * a[u] + mu1 * b[u];
            }
        }

        float outv = 0.f;
        #pragma unroll
        for (int i = 0; i < 16; ++i) {
            float s = tpl[i];
            s += __shfl_xor(s, 1, 16);
            s += __shfl_xor(s, 2, 16);
            s += __shfl_xor(s, 4, 16);
            s += __shfl_xor(s, 8, 16);
            if (qq == i) outv = s;
        }
        size_t mg = (size_t)mb * 128 + p * 32 + mloc;
        tp[(size_t)kt * MM * 16 + mg * 16 + qq] = outv;
        __syncthreads();
    }
}

// ---------------- sequential scan ----------------
__device__ __forceinline__ void scan_step(float (&C)[8], float (&tk)[8], int t,
                                          const float* base, size_t KS, float* ob) {
    float nw = 0.f;
    #pragma unroll
    for (int k = 0; k < 8; ++k) nw += C[k] * tk[k];
    ob[(size_t)t * 16] = nw;
    if (t + 8 < TT) {
        #pragma unroll
        for (int k = 0; k < 8; ++k) C[k] = base[(size_t)k * KS + (size_t)(t + 8) * 16];
    }
    float w = __expf(__expf(nw));
    float s = w;
    s += __shfl_xor(s, 1, 16);
    s += __shfl_xor(s, 2, 16);
    s += __shfl_xor(s, 4, 16);
    s += __shfl_xor(s, 8, 16);
    float tl = w / s;
    #pragma unroll
    for (int k = 0; k < 8; ++k) tk[k] = __shfl(tl, k, 16);
}

__global__ void k_scan(const float* __restrict__ tp, float* __restrict__ out) {
    const int b = blockIdx.x;
    const int l = threadIdx.x;
    if (l >= 16) return;
    const size_t KS = (size_t)MM * 16;
    const float* base = tp + (size_t)b * TT * 16 + l;
    float* ob = out + (size_t)b * TT * 16 + l;
    float tk[8];
    #pragma unroll
    for (int k = 0; k < 8; ++k) tk[k] = 1.f / 16.f;
    float c0[8], c1[8], c2[8], c3[8], c4[8], c5[8], c6[8], c7[8];
    #pragma unroll
    for (int k = 0; k < 8; ++k) {
        c0[k] = base[(size_t)k * KS + 0 * 16];
        c1[k] = base[(size_t)k * KS + 1 * 16];
        c2[k] = base[(size_t)k * KS + 2 * 16];
        c3[k] = base[(size_t)k * KS + 3 * 16];
        c4[k] = base[(size_t)k * KS + 4 * 16];
        c5[k] = base[(size_t)k * KS + 5 * 16];
        c6[k] = base[(size_t)k * KS + 6 * 16];
        c7[k] = base[(size_t)k * KS + 7 * 16];
    }
    for (int t0 = 0; t0 < TT; t0 += 8) {
        scan_step(c0, tk, t0 + 0, base, KS, ob);
        scan_step(c1, tk, t0 + 1, base, KS, ob);
        scan_step(c2, tk, t0 + 2, base, KS, ob);
        scan_step(c3, tk, t0 + 3, base, KS, ob);
        scan_step(c4, tk, t0 + 4, base, KS, ob);
        scan_step(c5, tk, t0 + 5, base, KS, ob);
        scan_step(c6, tk, t0 + 6, base, KS, ob);
        scan_step(c7, tk, t0 + 7, base, KS, ob);
    }
}

extern "C" void kernel_launch(void* const* d_in, const int* in_sizes, int n_in,
                              void* d_out, int out_size, void* d_ws, size_t ws_size,
                              hipStream_t stream) {
    const float* x  = (const float*)d_in[0];
    const float* W  = (const float*)d_in[1];
    const float* b  = (const float*)d_in[2];
    const float* pi = (const float*)d_in[3];
    float* ws = (float*)d_ws;
    float* sp = ws;                              // 32768 floats (8 * 4096)
    short* Bp = (short*)(ws + 32768);            // 2,097,152 shorts = 1,048,576 float slots
    float* tp = ws + 32768 + 1048576;            // 8,388,608 floats: [kt][m][l]
    float* out = (float*)d_out;

    k_prep_sp<<<dim3(8), dim3(256), 0, stream>>>(pi, sp);
    k_prep_b<<<dim3(512), dim3(256), 0, stream>>>(W, Bp);
    k_forest<<<dim3(8, 512), dim3(512), 0, stream>>>(x, Bp, b, sp, tp);
    k_scan<<<dim3(BB), dim3(64), 0, stream>>>(tp, out);
}

// Round 3
// 1299.893 us; speedup vs baseline: 2.3531x; 1.4127x over previous
//
#include <hip/hip_runtime.h>

#define KT 8
#define NN 255
#define LL 16
#define DD 512
#define BB 32
#define TT 2048
#define MM (BB*TT)      // 65536

typedef short short8 __attribute__((ext_vector_type(8)));
typedef float floatx4 __attribute__((ext_vector_type(4)));

__device__ __forceinline__ unsigned bf16_rne(float v) {
    unsigned u = __float_as_uint(v);
    return (u + 0x7FFFu + ((u >> 16) & 1u)) >> 16;
}

__device__ __forceinline__ void gll16(const char* g, char* l) {
    __builtin_amdgcn_global_load_lds(
        (const __attribute__((address_space(1))) unsigned int*)g,
        (__attribute__((address_space(3))) unsigned int*)l, 16, 0, 0);
}

// ---------------- prep: split x into bf16 hi/lo planes ----------------
__global__ void k_prep_x(const float* __restrict__ x, short* __restrict__ xh,
                         short* __restrict__ xl) {
    size_t g = (size_t)blockIdx.x * 256 + threadIdx.x;   // 4,194,304 threads
    const float4* xv = (const float4*)x;
    float4 a = xv[g * 2], b = xv[g * 2 + 1];
    float v[8] = {a.x, a.y, a.z, a.w, b.x, b.y, b.z, b.w};
    short8 hh, ll;
    #pragma unroll
    for (int j = 0; j < 8; ++j) {
        unsigned h = bf16_rne(v[j]);
        hh[j] = (short)h;
        ll[j] = (short)bf16_rne(v[j] - __uint_as_float(h << 16));
    }
    ((short8*)xh)[g] = hh;
    ((short8*)xl)[g] = ll;
}

// ---------------- prep: softmax(pi) dense: spd[kt][leaf][l] ----------------
__global__ void k_prep_sp(const float* __restrict__ pi, float* __restrict__ spd) {
    int g = blockIdx.x * blockDim.x + threadIdx.x;   // 2048
    const float* p = pi + (size_t)g * LL;
    float v[LL];
    float mx = -1e30f;
    #pragma unroll
    for (int l = 0; l < LL; ++l) { v[l] = p[l]; mx = fmaxf(mx, v[l]); }
    float s = 0.f;
    #pragma unroll
    for (int l = 0; l < LL; ++l) { v[l] = __expf(v[l] - mx); s += v[l]; }
    const float inv = 1.0f / s;
    float* o = spd + (size_t)g * LL;
    #pragma unroll
    for (int l = 0; l < LL; ++l) o[l] = v[l] * inv;
}

// ---------------- prep: W -> MFMA B-frag order, split bf16 hi/lo ----------------
// Bp layout: [kt][kb16][nt16][hl2][lane64][8 bf16]
__global__ void k_prep_b(const float* __restrict__ W, short* __restrict__ Bp) {
    int g = blockIdx.x * 256 + threadIdx.x;          // 131072
    int lane = g & 63;
    int nt = (g >> 6) & 15;
    int kb = (g >> 10) & 15;
    int kt = g >> 14;
    int n = nt * 16 + (lane & 15);
    int k0 = kb * 32 + ((lane >> 4) << 3);
    short8 hh = {0,0,0,0,0,0,0,0}, ll = {0,0,0,0,0,0,0,0};
    if (n < NN) {
        const float* wp = W + ((size_t)kt * NN + n) * DD + k0;
        floatx4 a = *(const floatx4*)wp;
        floatx4 b = *(const floatx4*)(wp + 4);
        float xv[8] = {a[0], a[1], a[2], a[3], b[0], b[1], b[2], b[3]};
        #pragma unroll
        for (int j = 0; j < 8; ++j) {
            unsigned h = bf16_rne(xv[j]);
            hh[j] = (short)h;
            ll[j] = (short)bf16_rne(xv[j] - __uint_as_float(h << 16));
        }
    }
    size_t base = ((((size_t)kt * 16 + kb) * 16 + nt) * 2) * 64;   // short8 units
    ((short8*)Bp)[base + lane] = hh;
    ((short8*)Bp)[base + 64 + lane] = ll;
}

// ---------------- prep: sp -> MFMA B-frag order, split hi/lo ----------------
// spf layout: [kt][ks8][hl2][lane64][8 bf16]
__global__ void k_prep_spf(const float* __restrict__ spd, short* __restrict__ spf) {
    int g = blockIdx.x * 64 + threadIdx.x;           // 4096
    int lane = g & 63;
    int ks = (g >> 6) & 7;
    int kt = g >> 9;
    int n = lane & 15;
    int oct = lane >> 4;
    short8 hh, ll;
    #pragma unroll
    for (int j = 0; j < 8; ++j) {
        int leaf = ks * 32 + oct * 8 + j;
        float v = spd[((size_t)kt * 256 + leaf) * 16 + n];
        unsigned h = bf16_rne(v);
        hh[j] = (short)h;
        ll[j] = (short)bf16_rne(v - __uint_as_float(h << 16));
    }
    size_t base = ((size_t)(kt * 8 + ks) * 2) * 64;
    ((short8*)spf)[base + lane] = hh;
    ((short8*)spf)[base + 64 + lane] = ll;
}

// ---------------- fused forest kernel ----------------
__launch_bounds__(512, 2)
__global__ void k_forest(const short* __restrict__ xh, const short* __restrict__ xl,
                         const short* __restrict__ Bp, const float* __restrict__ bias,
                         const short* __restrict__ spf, float* __restrict__ tp) {
    __shared__ __align__(16) char smem[65536];
    const int tid  = threadIdx.x;
    const int lane = tid & 63;
    const int wv   = tid >> 6;
    const int wr   = wv >> 1;       // m-group 0..3
    const int wc   = wv & 1;        // n-half
    const int kt   = blockIdx.x;
    const int mb   = blockIdx.y;
    const int oct  = lane >> 4;

    const int mrow0 = mb * 128 + wr * 32;
    const short* xhb = xh + (size_t)(mrow0 + (lane & 15)) * DD + (oct << 3);
    const short* xlb = xl + (size_t)(mrow0 + (lane & 15)) * DD + (oct << 3);
    const char* bsrc = (const char*)Bp + (size_t)kt * 16 * 32768;

    float breg[8];
    #pragma unroll
    for (int ntl = 0; ntl < 8; ++ntl) {
        int n = wc * 128 + ntl * 16 + (lane & 15);
        breg[ntl] = (n < NN) ? bias[kt * NN + n] : 0.f;
    }

    floatx4 acc[2][8];
    #pragma unroll
    for (int mt = 0; mt < 2; ++mt)
        #pragma unroll
        for (int ntl = 0; ntl < 8; ++ntl)
            acc[mt][ntl] = (floatx4){0.f, 0.f, 0.f, 0.f};

    short8 ahc[2], alc[2], ahn[2], aln[2];

    // prologue: stage kb=0, load A(0)
    #pragma unroll
    for (int i = 0; i < 4; ++i)
        gll16(bsrc + i * 8192 + tid * 16, (char*)smem + i * 8192 + tid * 16);
    #pragma unroll
    for (int mt = 0; mt < 2; ++mt) {
        ahc[mt] = *(const short8*)(xhb + (size_t)mt * 16 * DD);
        alc[mt] = *(const short8*)(xlb + (size_t)mt * 16 * DD);
    }
    __syncthreads();

    #pragma unroll 2
    for (int kb = 0; kb < 16; ++kb) {
        char* cur = (char*)smem + ((kb & 1) ? 32768 : 0);
        char* nxt = (char*)smem + ((kb & 1) ? 0 : 32768);
        if (kb < 15) {
            const char* s = bsrc + (size_t)(kb + 1) * 32768;
            #pragma unroll
            for (int i = 0; i < 4; ++i)
                gll16(s + i * 8192 + tid * 16, nxt + i * 8192 + tid * 16);
            #pragma unroll
            for (int mt = 0; mt < 2; ++mt) {
                ahn[mt] = *(const short8*)(xhb + (size_t)mt * 16 * DD + (kb + 1) * 32);
                aln[mt] = *(const short8*)(xlb + (size_t)mt * 16 * DD + (kb + 1) * 32);
            }
        }
        const short8* bf = (const short8*)cur;
        #pragma unroll
        for (int ntl = 0; ntl < 8; ++ntl) {
            const int nt = wc * 8 + ntl;
            short8 bh = bf[(size_t)(nt * 2 + 0) * 64 + lane];
            short8 bl = bf[(size_t)(nt * 2 + 1) * 64 + lane];
            #pragma unroll
            for (int mt = 0; mt < 2; ++mt) {
                acc[mt][ntl] = __builtin_amdgcn_mfma_f32_16x16x32_bf16(ahc[mt], bh, acc[mt][ntl], 0, 0, 0);
                acc[mt][ntl] = __builtin_amdgcn_mfma_f32_16x16x32_bf16(ahc[mt], bl, acc[mt][ntl], 0, 0, 0);
                acc[mt][ntl] = __builtin_amdgcn_mfma_f32_16x16x32_bf16(alc[mt], bh, acc[mt][ntl], 0, 0, 0);
            }
        }
        __syncthreads();
        #pragma unroll
        for (int mt = 0; mt < 2; ++mt) {
            ahc[mt] = ahn[mt]; alc[mt] = aln[mt];
        }
    }

    // ---------------- epilogue ----------------
    float* dls = (float*)smem;                       // [32][260] fp32
    const short8* spl = (const short8*)((char*)smem + 33280);   // 16 KB frag copy
    floatx4* ps = (floatx4*)((char*)smem + 49664);   // partial D-frags, 8 KB

    {   // stage sp frags (LDS region is free: post-barrier)
        const floatx4* src = (const floatx4*)(spf + (size_t)kt * 8192);
        floatx4* dst = (floatx4*)((char*)smem + 33280);
        dst[tid] = src[tid];
        dst[512 + tid] = src[512 + tid];
    }

    const int mtile = wv & 1;
    const int wg = wv >> 1;
    const int mloc = mtile * 16 + (lane & 15);

    #pragma unroll 1
    for (int p = 0; p < 4; ++p) {
        __syncthreads();
        if (wr == p) {
            #pragma unroll
            for (int mt = 0; mt < 2; ++mt)
                #pragma unroll
                for (int ntl = 0; ntl < 8; ++ntl)
                    #pragma unroll
                    for (int i = 0; i < 4; ++i) {
                        float lg = acc[mt][ntl][i] + breg[ntl];
                        float dv = 1.f / (1.f + __expf(-lg));
                        int mrow = mt * 16 + oct * 4 + i;
                        int n = wc * 128 + ntl * 16 + (lane & 15);
                        dls[mrow * 260 + n] = dv;
                    }
        }
        __syncthreads();

        const float* dm = dls + mloc * 260;
        floatx4 pacc = (floatx4){0.f, 0.f, 0.f, 0.f};
        #pragma unroll
        for (int kss = 0; kss < 2; ++kss) {
            const int ks = wg * 2 + kss;
            const int leaf0 = ks * 32 + oct * 8;
            float d0 = dm[0];
            float d1 = dm[1 + (leaf0 >> 7)];
            float d2 = dm[3 + (leaf0 >> 6)];
            float d3 = dm[7 + (leaf0 >> 5)];
            float d4 = dm[15 + (leaf0 >> 4)];
            float d5 = dm[31 + (leaf0 >> 3)];
            float n6a = dm[63 + (leaf0 >> 2)];
            float n6b = dm[64 + (leaf0 >> 2)];
            float v70 = dm[127 + (leaf0 >> 1)];
            float v71 = dm[128 + (leaf0 >> 1)];
            float v72 = dm[129 + (leaf0 >> 1)];
            float v73 = dm[130 + (leaf0 >> 1)];
            float P = (((leaf0 >> 7) & 1) ? (1.f - d0) : d0)
                    * (((leaf0 >> 6) & 1) ? (1.f - d1) : d1)
                    * (((leaf0 >> 5) & 1) ? (1.f - d2) : d2)
                    * (((leaf0 >> 4) & 1) ? (1.f - d3) : d3)
                    * (((leaf0 >> 3) & 1) ? (1.f - d4) : d4);
            float pA = P * d5, pB = P * (1.f - d5);
            float q0 = pA * n6a, q1 = pA * (1.f - n6a);
            float q2 = pB * n6b, q3 = pB * (1.f - n6b);
            float mu[8];
            mu[0] = q0 * v70; mu[1] = q0 * (1.f - v70);
            mu[2] = q1 * v71; mu[3] = q1 * (1.f - v71);
            mu[4] = q2 * v72; mu[5] = q2 * (1.f - v72);
            mu[6] = q3 * v73; mu[7] = q3 * (1.f - v73);
            short8 mh, ml;
            #pragma unroll
            for (int j = 0; j < 8; ++j) {
                unsigned h = bf16_rne(mu[j]);
                mh[j] = (short)h;
                ml[j] = (short)bf16_rne(mu[j] - __uint_as_float(h << 16));
            }
            short8 sh = spl[(ks * 2 + 0) * 64 + lane];
            short8 sl = spl[(ks * 2 + 1) * 64 + lane];
            pacc = __builtin_amdgcn_mfma_f32_16x16x32_bf16(mh, sh, pacc, 0, 0, 0);
            pacc = __builtin_amdgcn_mfma_f32_16x16x32_bf16(mh, sl, pacc, 0, 0, 0);
            pacc = __builtin_amdgcn_mfma_f32_16x16x32_bf16(ml, sh, pacc, 0, 0, 0);
        }
        ps[(mtile * 4 + wg) * 64 + lane] = pacc;
        __syncthreads();
        if (wv < 2) {
            const int mt2 = wv;
            floatx4 r = ps[(mt2 * 4 + 0) * 64 + lane] + ps[(mt2 * 4 + 1) * 64 + lane]
                      + ps[(mt2 * 4 + 2) * 64 + lane] + ps[(mt2 * 4 + 3) * 64 + lane];
            #pragma unroll
            for (int i = 0; i < 4; ++i) {
                size_t mg = (size_t)mb * 128 + p * 32 + mt2 * 16 + oct * 4 + i;
                tp[mg * 128 + kt * 16 + (lane & 15)] = r[i];
            }
        }
    }
}

// ---------------- sequential scan ----------------
__device__ __forceinline__ float dpp_sum16(float v) {
    int i;
    i = __builtin_amdgcn_update_dpp(0, __float_as_int(v), 0xB1, 0xF, 0xF, true);
    v += __int_as_float(i);
    i = __builtin_amdgcn_update_dpp(0, __float_as_int(v), 0x4E, 0xF, 0xF, true);
    v += __int_as_float(i);
    i = __builtin_amdgcn_update_dpp(0, __float_as_int(v), 0x141, 0xF, 0xF, true);
    v += __int_as_float(i);
    i = __builtin_amdgcn_update_dpp(0, __float_as_int(v), 0x140, 0xF, 0xF, true);
    v += __int_as_float(i);
    return v;
}

__device__ __forceinline__ float rdl(float v, int k) {
    return __int_as_float(__builtin_amdgcn_readlane(__float_as_int(v), k));
}

#define SCAN_STEP(C, t) do { \
    float nw = ((C[0]*w0 + C[1]*w1) + (C[2]*w2 + C[3]*w3)) \
             + ((C[4]*w4 + C[5]*w5) + (C[6]*w6 + C[7]*w7)); \
    nw *= rinv; \
    ob[(size_t)(t) * 16] = nw; \
    float e1 = __expf(nw); \
    float wx = __expf(e1); \
    if ((t) + 8 < TT) { \
        _Pragma("unroll") \
        for (int k = 0; k < 8; ++k) C[k] = base[(size_t)((t) + 8) * 128 + k * 16]; \
    } \
    float ssum = dpp_sum16(wx); \
    rinv = __builtin_amdgcn_rcpf(ssum); \
    w0 = rdl(wx, 0); w1 = rdl(wx, 1); w2 = rdl(wx, 2); w3 = rdl(wx, 3); \
    w4 = rdl(wx, 4); w5 = rdl(wx, 5); w6 = rdl(wx, 6); w7 = rdl(wx, 7); \
} while (0)

__global__ void k_scan(const float* __restrict__ tp, float* __restrict__ out) {
    const int b = blockIdx.x;
    const int l = threadIdx.x;
    if (l >= 16) return;
    const float* base = tp + (size_t)b * TT * 128 + l;
    float* ob = out + (size_t)b * TT * 16 + l;
    float w0 = 1.f, w1 = 1.f, w2 = 1.f, w3 = 1.f, w4 = 1.f, w5 = 1.f, w6 = 1.f, w7 = 1.f;
    float rinv = 1.f / 16.f;
    float c0[8], c1[8], c2[8], c3[8], c4[8], c5[8], c6[8], c7[8];
    #pragma unroll
    for (int k = 0; k < 8; ++k) {
        c0[k] = base[(size_t)0 * 128 + k * 16];
        c1[k] = base[(size_t)1 * 128 + k * 16];
        c2[k] = base[(size_t)2 * 128 + k * 16];
        c3[k] = base[(size_t)3 * 128 + k * 16];
        c4[k] = base[(size_t)4 * 128 + k * 16];
        c5[k] = base[(size_t)5 * 128 + k * 16];
        c6[k] = base[(size_t)6 * 128 + k * 16];
        c7[k] = base[(size_t)7 * 128 + k * 16];
    }
    for (int t0 = 0; t0 < TT; t0 += 8) {
        SCAN_STEP(c0, t0 + 0);
        SCAN_STEP(c1, t0 + 1);
        SCAN_STEP(c2, t0 + 2);
        SCAN_STEP(c3, t0 + 3);
        SCAN_STEP(c4, t0 + 4);
        SCAN_STEP(c5, t0 + 5);
        SCAN_STEP(c6, t0 + 6);
        SCAN_STEP(c7, t0 + 7);
    }
}

extern "C" void kernel_launch(void* const* d_in, const int* in_sizes, int n_in,
                              void* d_out, int out_size, void* d_ws, size_t ws_size,
                              hipStream_t stream) {
    const float* x  = (const float*)d_in[0];
    const float* W  = (const float*)d_in[1];
    const float* b  = (const float*)d_in[2];
    const float* pi = (const float*)d_in[3];
    float* ws = (float*)d_ws;
    float* tp  = ws;                                   // 8,388,608 floats (32 MB)
    short* xh  = (short*)(ws + 8388608);               // 33,554,432 shorts (64 MB)
    short* xl  = xh + 33554432;                        // 64 MB
    short* Bp  = xl + 33554432;                        // 2,097,152 shorts (4 MB)
    short* spf = Bp + 2097152;                         // 65,536 shorts (128 KB)
    float* spd = (float*)(spf + 65536);                // 32,768 floats (128 KB)
    float* out = (float*)d_out;

    k_prep_x<<<dim3(16384), dim3(256), 0, stream>>>(x, xh, xl);
    k_prep_sp<<<dim3(8), dim3(256), 0, stream>>>(pi, spd);
    k_prep_b<<<dim3(512), dim3(256), 0, stream>>>(W, Bp);
    k_prep_spf<<<dim3(64), dim3(64), 0, stream>>>(spd, spf);
    k_forest<<<dim3(8, 512), dim3(512), 0, stream>>>(xh, xl, Bp, b, spf, tp);
    k_scan<<<dim3(BB), dim3(64), 0, stream>>>(tp, out);
}